// Round 1
// baseline (395.729 us; speedup 1.0000x reference)
//
#include <hip/hip_runtime.h>

// ---------------------------------------------------------------------------
// EfficientCrossAttention on MI355X (gfx950)
// B=4 T=4096 D=1024 ; N=2048 L=768 ; H=16 dh=64
//
// Pipeline (all on `stream`):
//   1. wprep:   Wq,Wk,Wv,Wh (K x 1024 f32) -> WT (1024 x K bf16)   [transpose+cvt]
//   2. ln1:     x1 -> nx1 bf16, x1 bf16 copy (fused, one read of x1)
//   3. ln2:     x2 -> nx2 bf16
//   4. gemm:    q = softmax_head(nx1 @ WqT + bq)   -> bf16   (fused softmax epilogue)
//               k = softmax_head(nx2 @ WkT + bk)   -> bf16
//               v =               nx2 @ WvT + bv   -> bf16
//   5. attn:    attnT[b,h][l][d] = sum_n k[b,n,h,d]*v[b,n,h,l]  (partials + reduce, bf16)
//   6. final:   out = x1 @ WhT + bh + q @ blockdiag(attn)
//               (y fused as 2 extra K-steps: per-wave head == 64-col tile half)
// ---------------------------------------------------------------------------

#define DEV __device__ __forceinline__

typedef unsigned short bf16_t;
typedef __attribute__((ext_vector_type(8))) __bf16 bf16x8;
typedef __attribute__((ext_vector_type(8))) unsigned short ushort8;
typedef __attribute__((ext_vector_type(4))) float f32x4;

DEV unsigned short f2bf(float f) {            // RNE float->bf16 (finite inputs)
  unsigned int u = __float_as_uint(f);
  unsigned int r = 0x7FFFu + ((u >> 16) & 1u);
  return (unsigned short)((u + r) >> 16);
}
DEV float bf2f(unsigned short u) { return __uint_as_float(((unsigned int)u) << 16); }

DEV void gld16(const void* g, void* l) {      // async global->LDS, 16B/lane
  __builtin_amdgcn_global_load_lds((__attribute__((address_space(1))) void*)g,
                                   (__attribute__((address_space(3))) void*)l, 16, 0, 0);
}

// ---------------------------------------------------------------------------
// Weight prep: WT[n][k] = bf16(W[k][n]).  32x32 tiles, LDS transpose.
// tiles: Wq 1024 | Wk 768 | Wv 768 | Wh 1024  => 3584 blocks
// ---------------------------------------------------------------------------
__global__ __launch_bounds__(256) void wprep_kernel(
    const float* __restrict__ Wq, const float* __restrict__ Wk,
    const float* __restrict__ Wv, const float* __restrict__ Wh,
    bf16_t* __restrict__ WqT, bf16_t* __restrict__ WkT,
    bf16_t* __restrict__ WvT, bf16_t* __restrict__ WhT) {
  int t = blockIdx.x;
  const float* src; bf16_t* dst; int K;
  if (t < 1024)      { src = Wq; dst = WqT; K = 1024; }
  else if (t < 1792) { src = Wk; dst = WkT; K = 768;  t -= 1024; }
  else if (t < 2560) { src = Wv; dst = WvT; K = 768;  t -= 1792; }
  else               { src = Wh; dst = WhT; K = 1024; t -= 2560; }
  int tk = t >> 5, tn = t & 31;
  __shared__ float tile[32][33];
  int tx = threadIdx.x & 31, ty = threadIdx.x >> 5;
#pragma unroll
  for (int i = 0; i < 4; ++i) {
    int r = ty + i * 8;
    tile[r][tx] = src[(size_t)(tk * 32 + r) * 1024 + tn * 32 + tx];
  }
  __syncthreads();
#pragma unroll
  for (int i = 0; i < 4; ++i) {
    int r = ty + i * 8;
    dst[(size_t)(tn * 32 + r) * K + tk * 32 + tx] = f2bf(tile[tx][r]);
  }
}

// ---------------------------------------------------------------------------
// LayerNorm x1 (rows of 1024) -> nx1 bf16 and x1 bf16 copy
// ---------------------------------------------------------------------------
__global__ __launch_bounds__(256) void ln1_kernel(
    const float* __restrict__ x1, const float* __restrict__ g1, const float* __restrict__ b1,
    bf16_t* __restrict__ nx1, bf16_t* __restrict__ x1b) {
  int row = blockIdx.x, tid = threadIdx.x;
  size_t base = (size_t)row * 1024;
  float4 xv = *(const float4*)&x1[base + tid * 4];
  float s  = xv.x + xv.y + xv.z + xv.w;
  float s2 = xv.x * xv.x + xv.y * xv.y + xv.z * xv.z + xv.w * xv.w;
#pragma unroll
  for (int off = 32; off >= 1; off >>= 1) {
    s  += __shfl_down(s, off);
    s2 += __shfl_down(s2, off);
  }
  __shared__ float red[8];
  int wid = tid >> 6;
  if ((tid & 63) == 0) { red[wid] = s; red[4 + wid] = s2; }
  __syncthreads();
  s  = red[0] + red[1] + red[2] + red[3];
  s2 = red[4] + red[5] + red[6] + red[7];
  float mu = s * (1.0f / 1024.0f);
  float var = s2 * (1.0f / 1024.0f) - mu * mu;
  float rs = rsqrtf(var + 1e-5f);
  float4 gv = *(const float4*)&g1[tid * 4];
  float4 bv = *(const float4*)&b1[tid * 4];
  ushort4 pn, px;
  pn.x = f2bf((xv.x - mu) * rs * gv.x + bv.x);
  pn.y = f2bf((xv.y - mu) * rs * gv.y + bv.y);
  pn.z = f2bf((xv.z - mu) * rs * gv.z + bv.z);
  pn.w = f2bf((xv.w - mu) * rs * gv.w + bv.w);
  px.x = f2bf(xv.x); px.y = f2bf(xv.y); px.z = f2bf(xv.z); px.w = f2bf(xv.w);
  *(ushort4*)&nx1[base + tid * 4] = pn;
  *(ushort4*)&x1b[base + tid * 4] = px;
}

// ---------------------------------------------------------------------------
// LayerNorm x2 (rows of 768) -> nx2 bf16
// ---------------------------------------------------------------------------
__global__ __launch_bounds__(256) void ln2_kernel(
    const float* __restrict__ x2, const float* __restrict__ g2, const float* __restrict__ b2,
    bf16_t* __restrict__ nx2) {
  int row = blockIdx.x, tid = threadIdx.x;
  size_t base = (size_t)row * 768;
  float a0 = x2[base + tid], a1 = x2[base + tid + 256], a2 = x2[base + tid + 512];
  float s = a0 + a1 + a2;
  float s2 = a0 * a0 + a1 * a1 + a2 * a2;
#pragma unroll
  for (int off = 32; off >= 1; off >>= 1) {
    s  += __shfl_down(s, off);
    s2 += __shfl_down(s2, off);
  }
  __shared__ float red[8];
  int wid = tid >> 6;
  if ((tid & 63) == 0) { red[wid] = s; red[4 + wid] = s2; }
  __syncthreads();
  s  = red[0] + red[1] + red[2] + red[3];
  s2 = red[4] + red[5] + red[6] + red[7];
  float mu = s * (1.0f / 768.0f);
  float var = s2 * (1.0f / 768.0f) - mu * mu;
  float rs = rsqrtf(var + 1e-5f);
  nx2[base + tid]       = f2bf((a0 - mu) * rs * g2[tid]       + b2[tid]);
  nx2[base + tid + 256] = f2bf((a1 - mu) * rs * g2[tid + 256] + b2[tid + 256]);
  nx2[base + tid + 512] = f2bf((a2 - mu) * rs * g2[tid + 512] + b2[tid + 512]);
}

// ---------------------------------------------------------------------------
// GEMM (m97 structure): C[M][1024] = A[M][K] @ WT[1024][K]^T + bias
// 128x128 tile, 4 waves (2x2 of 64x64), 16x16x32 bf16 MFMA, BK=32,
// global_load_lds width-16 staging, single-buffer two-barrier K-loop.
// Epilogue: optional per-head softmax (wave owns one 64-col head:
//   row lives in one 16-lane quad x 4 regs -> 4-reg max + shfl_xor{1,2,4,8}).
// Output bf16, ldc=1024.
// ---------------------------------------------------------------------------
__global__ __launch_bounds__(256) void gemm_qkv_kernel(
    const bf16_t* __restrict__ A, const bf16_t* __restrict__ WT,
    const float* __restrict__ bias, bf16_t* __restrict__ out,
    int K, int do_softmax) {
  __shared__ bf16_t As[128 * 32];
  __shared__ bf16_t Bs[128 * 32];
  int tid = threadIdx.x;
  int bn = blockIdx.x, bm = blockIdx.y;
  int lane = tid & 63, wid = tid >> 6;
  int wm = wid & 1, wn = wid >> 1;
  f32x4 acc[4][4];
#pragma unroll
  for (int i = 0; i < 4; ++i)
#pragma unroll
    for (int j = 0; j < 4; ++j) acc[i][j] = {0.f, 0.f, 0.f, 0.f};
  int nk = K >> 5;
  const bf16_t* Ab = A  + (size_t)bm * 128 * K;
  const bf16_t* Bb = WT + (size_t)bn * 128 * K;
  for (int kt = 0; kt < nk; ++kt) {
    __syncthreads();
#pragma unroll
    for (int i = 0; i < 2; ++i) {
      int c = i * 256 + tid;
      gld16(Ab + (size_t)(c >> 2) * K + kt * 32 + (c & 3) * 8, (void*)(As + c * 8));
      gld16(Bb + (size_t)(c >> 2) * K + kt * 32 + (c & 3) * 8, (void*)(Bs + c * 8));
    }
    __syncthreads();
    bf16x8 af[4], bfr[4];
#pragma unroll
    for (int mi = 0; mi < 4; ++mi)
      af[mi] = *(const bf16x8*)&As[(wm * 64 + mi * 16 + (lane & 15)) * 32 + (lane >> 4) * 8];
#pragma unroll
    for (int ni = 0; ni < 4; ++ni)
      bfr[ni] = *(const bf16x8*)&Bs[(wn * 64 + ni * 16 + (lane & 15)) * 32 + (lane >> 4) * 8];
#pragma unroll
    for (int mi = 0; mi < 4; ++mi)
#pragma unroll
      for (int ni = 0; ni < 4; ++ni)
        acc[mi][ni] = __builtin_amdgcn_mfma_f32_16x16x32_bf16(af[mi], bfr[ni], acc[mi][ni], 0, 0, 0);
  }
  int colg0 = bn * 128 + wn * 64;
  float bvv[4];
#pragma unroll
  for (int ni = 0; ni < 4; ++ni) bvv[ni] = bias[colg0 + ni * 16 + (lane & 15)];
#pragma unroll
  for (int mi = 0; mi < 4; ++mi) {
#pragma unroll
    for (int r = 0; r < 4; ++r) {
      int row = bm * 128 + wm * 64 + mi * 16 + (lane >> 4) * 4 + r;
      float vx[4];
#pragma unroll
      for (int ni = 0; ni < 4; ++ni) vx[ni] = acc[mi][ni][r] + bvv[ni];
      if (do_softmax) {
        float mx = fmaxf(fmaxf(vx[0], vx[1]), fmaxf(vx[2], vx[3]));
#pragma unroll
        for (int off = 1; off < 16; off <<= 1) mx = fmaxf(mx, __shfl_xor(mx, off));
        float ssum = 0.f;
#pragma unroll
        for (int ni = 0; ni < 4; ++ni) { vx[ni] = __expf(vx[ni] - mx); ssum += vx[ni]; }
#pragma unroll
        for (int off = 1; off < 16; off <<= 1) ssum += __shfl_xor(ssum, off);
        float inv = 1.0f / ssum;
#pragma unroll
        for (int ni = 0; ni < 4; ++ni) vx[ni] *= inv;
      }
#pragma unroll
      for (int ni = 0; ni < 4; ++ni)
        out[(size_t)row * 1024 + colg0 + ni * 16 + (lane & 15)] = f2bf(vx[ni]);
    }
  }
}

// ---------------------------------------------------------------------------
// attn partials: block = (bh, n-chunk of 256); acc 64x64 outer products.
// partial[bh][c][d][l] fp32
// ---------------------------------------------------------------------------
__global__ __launch_bounds__(256) void attn_partial_kernel(
    const bf16_t* __restrict__ kq, const bf16_t* __restrict__ vq,
    float* __restrict__ part) {
  int bh = blockIdx.x >> 3, c = blockIdx.x & 7;
  int b = bh >> 4, h = bh & 15;
  int tid = threadIdx.x;
  int td = tid & 15, tl = tid >> 4;
  __shared__ float ks[32][64];
  __shared__ float vs[32][64];
  float acc[4][4];
#pragma unroll
  for (int i = 0; i < 4; ++i)
#pragma unroll
    for (int j = 0; j < 4; ++j) acc[i][j] = 0.f;
  for (int s = 0; s < 8; ++s) {
    __syncthreads();
    int nr = tid >> 3, col = (tid & 7) * 8;
    int n = c * 256 + s * 32 + nr;
    size_t goff = ((size_t)(b * 2048 + n)) * 1024 + h * 64 + col;
    ushort8 lk = *(const ushort8*)&kq[goff];
    ushort8 lv = *(const ushort8*)&vq[goff];
#pragma unroll
    for (int j = 0; j < 8; ++j) {
      ks[nr][col + j] = bf2f(lk[j]);
      vs[nr][col + j] = bf2f(lv[j]);
    }
    __syncthreads();
#pragma unroll
    for (int nn = 0; nn < 32; ++nn) {
      float4 kv = *(const float4*)&ks[nn][td * 4];
      float4 vv = *(const float4*)&vs[nn][tl * 4];
      float ka[4] = {kv.x, kv.y, kv.z, kv.w};
      float va[4] = {vv.x, vv.y, vv.z, vv.w};
#pragma unroll
      for (int i = 0; i < 4; ++i)
#pragma unroll
        for (int j = 0; j < 4; ++j) acc[i][j] += ka[i] * va[j];
    }
  }
#pragma unroll
  for (int i = 0; i < 4; ++i)
#pragma unroll
    for (int j = 0; j < 4; ++j) {
      int d = td * 4 + i, l = tl * 4 + j;
      part[(((size_t)bh * 8 + c) * 64 + d) * 64 + l] = acc[i][j];
    }
}

// attnT[bh][l][d] = bf16( sum_c partial[bh][c][d][l] )   (k-contiguous for MFMA B)
__global__ __launch_bounds__(256) void attn_finalize_kernel(
    const float* __restrict__ part, bf16_t* __restrict__ attnT) {
  int bh = blockIdx.x, tid = threadIdx.x;
  for (int t = tid; t < 4096; t += 256) {
    int d = t >> 6, l = t & 63;
    float s = 0.f;
#pragma unroll
    for (int c = 0; c < 8; ++c)
      s += part[(((size_t)bh * 8 + c) * 64 + d) * 64 + l];
    attnT[((size_t)bh * 64 + l) * 64 + d] = f2bf(s);
  }
}

// ---------------------------------------------------------------------------
// Final GEMM: out = x1 @ WhT^T + bh + y, fp32 out.
// K-loop: 32 steps on (x1b, WhT) then 2 steps on (q, attnT block-diagonal):
//   wave_n==0 head = 2*bn (q cols bn*128+..), wave_n==1 head = 2*bn+1 (+64).
//   Bs rows n=0..127 <- attnT[b][2bn + n/64][n%64][k2*32..] (contiguous, stride 64).
// ---------------------------------------------------------------------------
__global__ __launch_bounds__(256) void gemm_final_kernel(
    const bf16_t* __restrict__ A, const bf16_t* __restrict__ WT,
    const float* __restrict__ bias, const bf16_t* __restrict__ qb,
    const bf16_t* __restrict__ attnT, float* __restrict__ out) {
  __shared__ bf16_t As [128 * 32];
  __shared__ bf16_t As2[128 * 32];
  __shared__ bf16_t Bs [128 * 32];
  const int K = 1024;
  int tid = threadIdx.x;
  int bn = blockIdx.x, bm = blockIdx.y;
  int lane = tid & 63, wid = tid >> 6;
  int wm = wid & 1, wn = wid >> 1;
  int b = bm >> 5;   // T=4096 -> 32 m-tiles per batch
  f32x4 acc[4][4];
#pragma unroll
  for (int i = 0; i < 4; ++i)
#pragma unroll
    for (int j = 0; j < 4; ++j) acc[i][j] = {0.f, 0.f, 0.f, 0.f};
  const bf16_t* Ab = A  + (size_t)bm * 128 * K;
  const bf16_t* Bb = WT + (size_t)bn * 128 * K;
  for (int kt = 0; kt < 34; ++kt) {
    __syncthreads();
    if (kt < 32) {
#pragma unroll
      for (int i = 0; i < 2; ++i) {
        int c = i * 256 + tid;
        gld16(Ab + (size_t)(c >> 2) * K + kt * 32 + (c & 3) * 8, (void*)(As + c * 8));
        gld16(Bb + (size_t)(c >> 2) * K + kt * 32 + (c & 3) * 8, (void*)(Bs + c * 8));
      }
    } else {
      int k2 = kt - 32;
      const bf16_t* Aq = qb + (size_t)bm * 128 * 1024 + bn * 128 + k2 * 32;
      const bf16_t* Bt = attnT + ((size_t)b * 1024 + bn * 128) * 64 + k2 * 32;
#pragma unroll
      for (int i = 0; i < 2; ++i) {
        int c = i * 256 + tid;
        gld16(Aq +      (size_t)(c >> 2) * 1024 + (c & 3) * 8, (void*)(As  + c * 8));
        gld16(Aq + 64 + (size_t)(c >> 2) * 1024 + (c & 3) * 8, (void*)(As2 + c * 8));
        gld16(Bt +      (size_t)(c >> 2) * 64   + (c & 3) * 8, (void*)(Bs  + c * 8));
      }
    }
    __syncthreads();
    const bf16_t* Ap = (kt >= 32 && wn) ? As2 : As;
    bf16x8 af[4], bfr[4];
#pragma unroll
    for (int mi = 0; mi < 4; ++mi)
      af[mi] = *(const bf16x8*)&Ap[(wm * 64 + mi * 16 + (lane & 15)) * 32 + (lane >> 4) * 8];
#pragma unroll
    for (int ni = 0; ni < 4; ++ni)
      bfr[ni] = *(const bf16x8*)&Bs[(wn * 64 + ni * 16 + (lane & 15)) * 32 + (lane >> 4) * 8];
#pragma unroll
    for (int mi = 0; mi < 4; ++mi)
#pragma unroll
      for (int ni = 0; ni < 4; ++ni)
        acc[mi][ni] = __builtin_amdgcn_mfma_f32_16x16x32_bf16(af[mi], bfr[ni], acc[mi][ni], 0, 0, 0);
  }
  int colg0 = bn * 128 + wn * 64;
  float bvv[4];
#pragma unroll
  for (int ni = 0; ni < 4; ++ni) bvv[ni] = bias[colg0 + ni * 16 + (lane & 15)];
#pragma unroll
  for (int mi = 0; mi < 4; ++mi)
#pragma unroll
    for (int r = 0; r < 4; ++r) {
      int row = bm * 128 + wm * 64 + mi * 16 + (lane >> 4) * 4 + r;
#pragma unroll
      for (int ni = 0; ni < 4; ++ni)
        out[(size_t)row * 1024 + colg0 + ni * 16 + (lane & 15)] = acc[mi][ni][r] + bvv[ni];
    }
}

// ---------------------------------------------------------------------------
extern "C" void kernel_launch(void* const* d_in, const int* in_sizes, int n_in,
                              void* d_out, int out_size, void* d_ws, size_t ws_size,
                              hipStream_t stream) {
  const float* x1 = (const float*)d_in[0];
  const float* x2 = (const float*)d_in[1];
  const float* Wq = (const float*)d_in[2];
  const float* bq = (const float*)d_in[3];
  const float* Wk = (const float*)d_in[4];
  const float* bk = (const float*)d_in[5];
  const float* Wv = (const float*)d_in[6];
  const float* bv = (const float*)d_in[7];
  const float* Wh = (const float*)d_in[8];
  const float* bh = (const float*)d_in[9];
  const float* g1 = (const float*)d_in[10];
  const float* b1 = (const float*)d_in[11];
  const float* g2 = (const float*)d_in[12];
  const float* b2 = (const float*)d_in[13];
  float* out = (float*)d_out;

  char* w = (char*)d_ws;
  bf16_t* nx1  = (bf16_t*)w; w += (size_t)16384 * 1024 * 2;
  bf16_t* x1b  = (bf16_t*)w; w += (size_t)16384 * 1024 * 2;
  bf16_t* nx2  = (bf16_t*)w; w += (size_t)8192 * 768 * 2;
  bf16_t* WqT  = (bf16_t*)w; w += (size_t)1024 * 1024 * 2;
  bf16_t* WkT  = (bf16_t*)w; w += (size_t)1024 * 768 * 2;
  bf16_t* WvT  = (bf16_t*)w; w += (size_t)1024 * 768 * 2;
  bf16_t* WhT  = (bf16_t*)w; w += (size_t)1024 * 1024 * 2;
  bf16_t* qb   = (bf16_t*)w; w += (size_t)16384 * 1024 * 2;
  bf16_t* kbuf = (bf16_t*)w; w += (size_t)8192 * 1024 * 2;
  bf16_t* vbuf = (bf16_t*)w; w += (size_t)8192 * 1024 * 2;
  float*  part = (float*)w;  w += (size_t)64 * 8 * 64 * 64 * 4;
  bf16_t* attnT = (bf16_t*)w; w += (size_t)64 * 64 * 64 * 2;

  wprep_kernel<<<dim3(3584), dim3(256), 0, stream>>>(Wq, Wk, Wv, Wh, WqT, WkT, WvT, WhT);
  ln1_kernel<<<dim3(16384), dim3(256), 0, stream>>>(x1, g1, b1, nx1, x1b);
  ln2_kernel<<<dim3(8192), dim3(256), 0, stream>>>(x2, g2, b2, nx2);
  gemm_qkv_kernel<<<dim3(8, 128), dim3(256), 0, stream>>>(nx1, WqT, bq, qb, 1024, 1);
  gemm_qkv_kernel<<<dim3(8, 64),  dim3(256), 0, stream>>>(nx2, WkT, bk, kbuf, 768, 1);
  gemm_qkv_kernel<<<dim3(8, 64),  dim3(256), 0, stream>>>(nx2, WvT, bv, vbuf, 768, 0);
  attn_partial_kernel<<<dim3(512), dim3(256), 0, stream>>>(kbuf, vbuf, part);
  attn_finalize_kernel<<<dim3(64), dim3(256), 0, stream>>>(part, attnT);
  gemm_final_kernel<<<dim3(8, 128), dim3(256), 0, stream>>>(x1b, WhT, bh, qb, attnT, out);
}

// Round 2
// 345.210 us; speedup vs baseline: 1.1463x; 1.1463x over previous
//
#include <hip/hip_runtime.h>

// ---------------------------------------------------------------------------
// EfficientCrossAttention on MI355X (gfx950)
// B=4 T=4096 D=1024 ; N=2048 L=768 ; H=16 dh=64
//
// R1: merged q/k/v GEMM dispatch with XCD-aware block mapping (blocks sharing
//     an A-tile have id%8 == bm%8 -> same XCD L2), grid-transposed final GEMM.
// ---------------------------------------------------------------------------

#define DEV __device__ __forceinline__

typedef unsigned short bf16_t;
typedef __attribute__((ext_vector_type(8))) __bf16 bf16x8;
typedef __attribute__((ext_vector_type(8))) unsigned short ushort8;
typedef __attribute__((ext_vector_type(4))) float f32x4;

DEV unsigned short f2bf(float f) {            // RNE float->bf16 (finite inputs)
  unsigned int u = __float_as_uint(f);
  unsigned int r = 0x7FFFu + ((u >> 16) & 1u);
  return (unsigned short)((u + r) >> 16);
}
DEV float bf2f(unsigned short u) { return __uint_as_float(((unsigned int)u) << 16); }

DEV void gld16(const void* g, void* l) {      // async global->LDS, 16B/lane
  __builtin_amdgcn_global_load_lds((__attribute__((address_space(1))) void*)g,
                                   (__attribute__((address_space(3))) void*)l, 16, 0, 0);
}

// ---------------------------------------------------------------------------
// Weight prep: WT[n][k] = bf16(W[k][n]).  32x32 tiles, LDS transpose.
// ---------------------------------------------------------------------------
__global__ __launch_bounds__(256) void wprep_kernel(
    const float* __restrict__ Wq, const float* __restrict__ Wk,
    const float* __restrict__ Wv, const float* __restrict__ Wh,
    bf16_t* __restrict__ WqT, bf16_t* __restrict__ WkT,
    bf16_t* __restrict__ WvT, bf16_t* __restrict__ WhT) {
  int t = blockIdx.x;
  const float* src; bf16_t* dst; int K;
  if (t < 1024)      { src = Wq; dst = WqT; K = 1024; }
  else if (t < 1792) { src = Wk; dst = WkT; K = 768;  t -= 1024; }
  else if (t < 2560) { src = Wv; dst = WvT; K = 768;  t -= 1792; }
  else               { src = Wh; dst = WhT; K = 1024; t -= 2560; }
  int tk = t >> 5, tn = t & 31;
  __shared__ float tile[32][33];
  int tx = threadIdx.x & 31, ty = threadIdx.x >> 5;
#pragma unroll
  for (int i = 0; i < 4; ++i) {
    int r = ty + i * 8;
    tile[r][tx] = src[(size_t)(tk * 32 + r) * 1024 + tn * 32 + tx];
  }
  __syncthreads();
#pragma unroll
  for (int i = 0; i < 4; ++i) {
    int r = ty + i * 8;
    dst[(size_t)(tn * 32 + r) * K + tk * 32 + tx] = f2bf(tile[tx][r]);
  }
}

// ---------------------------------------------------------------------------
// LayerNorm x1 (rows of 1024) -> nx1 bf16 and x1 bf16 copy
// ---------------------------------------------------------------------------
__global__ __launch_bounds__(256) void ln1_kernel(
    const float* __restrict__ x1, const float* __restrict__ g1, const float* __restrict__ b1,
    bf16_t* __restrict__ nx1, bf16_t* __restrict__ x1b) {
  int row = blockIdx.x, tid = threadIdx.x;
  size_t base = (size_t)row * 1024;
  float4 xv = *(const float4*)&x1[base + tid * 4];
  float s  = xv.x + xv.y + xv.z + xv.w;
  float s2 = xv.x * xv.x + xv.y * xv.y + xv.z * xv.z + xv.w * xv.w;
#pragma unroll
  for (int off = 32; off >= 1; off >>= 1) {
    s  += __shfl_down(s, off);
    s2 += __shfl_down(s2, off);
  }
  __shared__ float red[8];
  int wid = tid >> 6;
  if ((tid & 63) == 0) { red[wid] = s; red[4 + wid] = s2; }
  __syncthreads();
  s  = red[0] + red[1] + red[2] + red[3];
  s2 = red[4] + red[5] + red[6] + red[7];
  float mu = s * (1.0f / 1024.0f);
  float var = s2 * (1.0f / 1024.0f) - mu * mu;
  float rs = rsqrtf(var + 1e-5f);
  float4 gv = *(const float4*)&g1[tid * 4];
  float4 bv = *(const float4*)&b1[tid * 4];
  ushort4 pn, px;
  pn.x = f2bf((xv.x - mu) * rs * gv.x + bv.x);
  pn.y = f2bf((xv.y - mu) * rs * gv.y + bv.y);
  pn.z = f2bf((xv.z - mu) * rs * gv.z + bv.z);
  pn.w = f2bf((xv.w - mu) * rs * gv.w + bv.w);
  px.x = f2bf(xv.x); px.y = f2bf(xv.y); px.z = f2bf(xv.z); px.w = f2bf(xv.w);
  *(ushort4*)&nx1[base + tid * 4] = pn;
  *(ushort4*)&x1b[base + tid * 4] = px;
}

// ---------------------------------------------------------------------------
// LayerNorm x2 (rows of 768) -> nx2 bf16
// ---------------------------------------------------------------------------
__global__ __launch_bounds__(256) void ln2_kernel(
    const float* __restrict__ x2, const float* __restrict__ g2, const float* __restrict__ b2,
    bf16_t* __restrict__ nx2) {
  int row = blockIdx.x, tid = threadIdx.x;
  size_t base = (size_t)row * 768;
  float a0 = x2[base + tid], a1 = x2[base + tid + 256], a2 = x2[base + tid + 512];
  float s = a0 + a1 + a2;
  float s2 = a0 * a0 + a1 * a1 + a2 * a2;
#pragma unroll
  for (int off = 32; off >= 1; off >>= 1) {
    s  += __shfl_down(s, off);
    s2 += __shfl_down(s2, off);
  }
  __shared__ float red[8];
  int wid = tid >> 6;
  if ((tid & 63) == 0) { red[wid] = s; red[4 + wid] = s2; }
  __syncthreads();
  s  = red[0] + red[1] + red[2] + red[3];
  s2 = red[4] + red[5] + red[6] + red[7];
  float mu = s * (1.0f / 768.0f);
  float var = s2 * (1.0f / 768.0f) - mu * mu;
  float rs = rsqrtf(var + 1e-5f);
  nx2[base + tid]       = f2bf((a0 - mu) * rs * g2[tid]       + b2[tid]);
  nx2[base + tid + 256] = f2bf((a1 - mu) * rs * g2[tid + 256] + b2[tid + 256]);
  nx2[base + tid + 512] = f2bf((a2 - mu) * rs * g2[tid + 512] + b2[tid + 512]);
}

// ---------------------------------------------------------------------------
// Merged q/k/v GEMM (m97 structure, BK=32, 128x128 tile, 4 waves).
// One dispatch, 2048 blocks:
//   [0,1024):     q = softmax(nx1 @ WqT + bq), M=16384, K=1024, bm=id&127
//   [1024,1536):  k = softmax(nx2 @ WkT + bk), M=8192,  K=768,  bm=id&63
//   [1536,2048):  v =          nx2 @ WvT + bv, M=8192,  K=768,  bm=id&63
// In every segment id % 8 == bm % 8 -> all blocks sharing an A-tile land on
// the same XCD (round-robin id%8) -> A staged from that XCD's L2, not HBM.
// ---------------------------------------------------------------------------
__global__ __launch_bounds__(256) void gemm_qkv_kernel(
    const bf16_t* __restrict__ nx1, const bf16_t* __restrict__ WqT,
    const float* __restrict__ bq, bf16_t* __restrict__ qout,
    const bf16_t* __restrict__ nx2, const bf16_t* __restrict__ WkT,
    const float* __restrict__ bk, bf16_t* __restrict__ kout,
    const bf16_t* __restrict__ WvT, const float* __restrict__ bv,
    bf16_t* __restrict__ vout) {
  __shared__ bf16_t As[128 * 32];
  __shared__ bf16_t Bs[128 * 32];
  int id = blockIdx.x;
  const bf16_t *A, *BT; const float* bias; bf16_t* out;
  int K, bm, bn, do_softmax;
  if (id < 1024) {
    A = nx1; BT = WqT; bias = bq; out = qout; K = 1024;
    bm = id & 127; bn = id >> 7; do_softmax = 1;
  } else if (id < 1536) {
    id -= 1024; A = nx2; BT = WkT; bias = bk; out = kout; K = 768;
    bm = id & 63; bn = id >> 6; do_softmax = 1;
  } else {
    id -= 1536; A = nx2; BT = WvT; bias = bv; out = vout; K = 768;
    bm = id & 63; bn = id >> 6; do_softmax = 0;
  }
  int tid = threadIdx.x;
  int lane = tid & 63, wid = tid >> 6;
  int wm = wid & 1, wn = wid >> 1;
  f32x4 acc[4][4];
#pragma unroll
  for (int i = 0; i < 4; ++i)
#pragma unroll
    for (int j = 0; j < 4; ++j) acc[i][j] = {0.f, 0.f, 0.f, 0.f};
  int nk = K >> 5;
  const bf16_t* Ab = A  + (size_t)bm * 128 * K;
  const bf16_t* Bb = BT + (size_t)bn * 128 * K;
  for (int kt = 0; kt < nk; ++kt) {
    __syncthreads();
#pragma unroll
    for (int i = 0; i < 2; ++i) {
      int c = i * 256 + tid;
      gld16(Ab + (size_t)(c >> 2) * K + kt * 32 + (c & 3) * 8, (void*)(As + c * 8));
      gld16(Bb + (size_t)(c >> 2) * K + kt * 32 + (c & 3) * 8, (void*)(Bs + c * 8));
    }
    __syncthreads();
    bf16x8 af[4], bfr[4];
#pragma unroll
    for (int mi = 0; mi < 4; ++mi)
      af[mi] = *(const bf16x8*)&As[(wm * 64 + mi * 16 + (lane & 15)) * 32 + (lane >> 4) * 8];
#pragma unroll
    for (int ni = 0; ni < 4; ++ni)
      bfr[ni] = *(const bf16x8*)&Bs[(wn * 64 + ni * 16 + (lane & 15)) * 32 + (lane >> 4) * 8];
#pragma unroll
    for (int mi = 0; mi < 4; ++mi)
#pragma unroll
      for (int ni = 0; ni < 4; ++ni)
        acc[mi][ni] = __builtin_amdgcn_mfma_f32_16x16x32_bf16(af[mi], bfr[ni], acc[mi][ni], 0, 0, 0);
  }
  int colg0 = bn * 128 + wn * 64;
  float bvv[4];
#pragma unroll
  for (int ni = 0; ni < 4; ++ni) bvv[ni] = bias[colg0 + ni * 16 + (lane & 15)];
#pragma unroll
  for (int mi = 0; mi < 4; ++mi) {
#pragma unroll
    for (int r = 0; r < 4; ++r) {
      int row = bm * 128 + wm * 64 + mi * 16 + (lane >> 4) * 4 + r;
      float vx[4];
#pragma unroll
      for (int ni = 0; ni < 4; ++ni) vx[ni] = acc[mi][ni][r] + bvv[ni];
      if (do_softmax) {
        float mx = fmaxf(fmaxf(vx[0], vx[1]), fmaxf(vx[2], vx[3]));
#pragma unroll
        for (int off = 1; off < 16; off <<= 1) mx = fmaxf(mx, __shfl_xor(mx, off));
        float ssum = 0.f;
#pragma unroll
        for (int ni = 0; ni < 4; ++ni) { vx[ni] = __expf(vx[ni] - mx); ssum += vx[ni]; }
#pragma unroll
        for (int off = 1; off < 16; off <<= 1) ssum += __shfl_xor(ssum, off);
        float inv = 1.0f / ssum;
#pragma unroll
        for (int ni = 0; ni < 4; ++ni) vx[ni] *= inv;
      }
#pragma unroll
      for (int ni = 0; ni < 4; ++ni)
        out[(size_t)row * 1024 + colg0 + ni * 16 + (lane & 15)] = f2bf(vx[ni]);
    }
  }
}

// ---------------------------------------------------------------------------
// attn partials: block = (bh, n-chunk of 256); acc 64x64 outer products.
// ---------------------------------------------------------------------------
__global__ __launch_bounds__(256) void attn_partial_kernel(
    const bf16_t* __restrict__ kq, const bf16_t* __restrict__ vq,
    float* __restrict__ part) {
  int bh = blockIdx.x >> 3, c = blockIdx.x & 7;
  int b = bh >> 4, h = bh & 15;
  int tid = threadIdx.x;
  int td = tid & 15, tl = tid >> 4;
  __shared__ float ks[32][64];
  __shared__ float vs[32][64];
  float acc[4][4];
#pragma unroll
  for (int i = 0; i < 4; ++i)
#pragma unroll
    for (int j = 0; j < 4; ++j) acc[i][j] = 0.f;
  for (int s = 0; s < 8; ++s) {
    __syncthreads();
    int nr = tid >> 3, col = (tid & 7) * 8;
    int n = c * 256 + s * 32 + nr;
    size_t goff = ((size_t)(b * 2048 + n)) * 1024 + h * 64 + col;
    ushort8 lk = *(const ushort8*)&kq[goff];
    ushort8 lv = *(const ushort8*)&vq[goff];
#pragma unroll
    for (int j = 0; j < 8; ++j) {
      ks[nr][col + j] = bf2f(lk[j]);
      vs[nr][col + j] = bf2f(lv[j]);
    }
    __syncthreads();
#pragma unroll
    for (int nn = 0; nn < 32; ++nn) {
      float4 kv = *(const float4*)&ks[nn][td * 4];
      float4 vv = *(const float4*)&vs[nn][tl * 4];
      float ka[4] = {kv.x, kv.y, kv.z, kv.w};
      float va[4] = {vv.x, vv.y, vv.z, vv.w};
#pragma unroll
      for (int i = 0; i < 4; ++i)
#pragma unroll
        for (int j = 0; j < 4; ++j) acc[i][j] += ka[i] * va[j];
    }
  }
#pragma unroll
  for (int i = 0; i < 4; ++i)
#pragma unroll
    for (int j = 0; j < 4; ++j) {
      int d = td * 4 + i, l = tl * 4 + j;
      part[(((size_t)bh * 8 + c) * 64 + d) * 64 + l] = acc[i][j];
    }
}

// attnT[bh][l][d] = bf16( sum_c partial[bh][c][d][l] )
__global__ __launch_bounds__(256) void attn_finalize_kernel(
    const float* __restrict__ part, bf16_t* __restrict__ attnT) {
  int bh = blockIdx.x, tid = threadIdx.x;
  for (int t = tid; t < 4096; t += 256) {
    int d = t >> 6, l = t & 63;
    float s = 0.f;
#pragma unroll
    for (int c = 0; c < 8; ++c)
      s += part[(((size_t)bh * 8 + c) * 64 + d) * 64 + l];
    attnT[((size_t)bh * 64 + l) * 64 + d] = f2bf(s);
  }
}

// ---------------------------------------------------------------------------
// Final GEMM: out = x1 @ WhT^T + bh + q @ blockdiag(attn), fp32 out.
// grid (128, 8): bm = blockIdx.x (fast) -> blocks sharing the x1b A-tile
// (8 bn values) land on the same XCD.
// ---------------------------------------------------------------------------
__global__ __launch_bounds__(256) void gemm_final_kernel(
    const bf16_t* __restrict__ A, const bf16_t* __restrict__ WT,
    const float* __restrict__ bias, const bf16_t* __restrict__ qb,
    const bf16_t* __restrict__ attnT, float* __restrict__ out) {
  __shared__ bf16_t As [128 * 32];
  __shared__ bf16_t As2[128 * 32];
  __shared__ bf16_t Bs [128 * 32];
  const int K = 1024;
  int tid = threadIdx.x;
  int bm = blockIdx.x, bn = blockIdx.y;
  int lane = tid & 63, wid = tid >> 6;
  int wm = wid & 1, wn = wid >> 1;
  int b = bm >> 5;   // T=4096 -> 32 m-tiles per batch
  f32x4 acc[4][4];
#pragma unroll
  for (int i = 0; i < 4; ++i)
#pragma unroll
    for (int j = 0; j < 4; ++j) acc[i][j] = {0.f, 0.f, 0.f, 0.f};
  const bf16_t* Ab = A  + (size_t)bm * 128 * K;
  const bf16_t* Bb = WT + (size_t)bn * 128 * K;
  for (int kt = 0; kt < 34; ++kt) {
    __syncthreads();
    if (kt < 32) {
#pragma unroll
      for (int i = 0; i < 2; ++i) {
        int c = i * 256 + tid;
        gld16(Ab + (size_t)(c >> 2) * K + kt * 32 + (c & 3) * 8, (void*)(As + c * 8));
        gld16(Bb + (size_t)(c >> 2) * K + kt * 32 + (c & 3) * 8, (void*)(Bs + c * 8));
      }
    } else {
      int k2 = kt - 32;
      const bf16_t* Aq = qb + (size_t)bm * 128 * 1024 + bn * 128 + k2 * 32;
      const bf16_t* Bt = attnT + ((size_t)b * 1024 + bn * 128) * 64 + k2 * 32;
#pragma unroll
      for (int i = 0; i < 2; ++i) {
        int c = i * 256 + tid;
        gld16(Aq +      (size_t)(c >> 2) * 1024 + (c & 3) * 8, (void*)(As  + c * 8));
        gld16(Aq + 64 + (size_t)(c >> 2) * 1024 + (c & 3) * 8, (void*)(As2 + c * 8));
        gld16(Bt +      (size_t)(c >> 2) * 64   + (c & 3) * 8, (void*)(Bs  + c * 8));
      }
    }
    __syncthreads();
    const bf16_t* Ap = (kt >= 32 && wn) ? As2 : As;
    bf16x8 af[4], bfr[4];
#pragma unroll
    for (int mi = 0; mi < 4; ++mi)
      af[mi] = *(const bf16x8*)&Ap[(wm * 64 + mi * 16 + (lane & 15)) * 32 + (lane >> 4) * 8];
#pragma unroll
    for (int ni = 0; ni < 4; ++ni)
      bfr[ni] = *(const bf16x8*)&Bs[(wn * 64 + ni * 16 + (lane & 15)) * 32 + (lane >> 4) * 8];
#pragma unroll
    for (int mi = 0; mi < 4; ++mi)
#pragma unroll
      for (int ni = 0; ni < 4; ++ni)
        acc[mi][ni] = __builtin_amdgcn_mfma_f32_16x16x32_bf16(af[mi], bfr[ni], acc[mi][ni], 0, 0, 0);
  }
  int colg0 = bn * 128 + wn * 64;
  float bvv[4];
#pragma unroll
  for (int ni = 0; ni < 4; ++ni) bvv[ni] = bias[colg0 + ni * 16 + (lane & 15)];
#pragma unroll
  for (int mi = 0; mi < 4; ++mi)
#pragma unroll
    for (int r = 0; r < 4; ++r) {
      int row = bm * 128 + wm * 64 + mi * 16 + (lane >> 4) * 4 + r;
#pragma unroll
      for (int ni = 0; ni < 4; ++ni)
        out[(size_t)row * 1024 + colg0 + ni * 16 + (lane & 15)] = acc[mi][ni][r] + bvv[ni];
    }
}

// ---------------------------------------------------------------------------
extern "C" void kernel_launch(void* const* d_in, const int* in_sizes, int n_in,
                              void* d_out, int out_size, void* d_ws, size_t ws_size,
                              hipStream_t stream) {
  const float* x1 = (const float*)d_in[0];
  const float* x2 = (const float*)d_in[1];
  const float* Wq = (const float*)d_in[2];
  const float* bq = (const float*)d_in[3];
  const float* Wk = (const float*)d_in[4];
  const float* bk = (const float*)d_in[5];
  const float* Wv = (const float*)d_in[6];
  const float* bv = (const float*)d_in[7];
  const float* Wh = (const float*)d_in[8];
  const float* bh = (const float*)d_in[9];
  const float* g1 = (const float*)d_in[10];
  const float* b1 = (const float*)d_in[11];
  const float* g2 = (const float*)d_in[12];
  const float* b2 = (const float*)d_in[13];
  float* out = (float*)d_out;

  char* w = (char*)d_ws;
  bf16_t* nx1  = (bf16_t*)w; w += (size_t)16384 * 1024 * 2;
  bf16_t* x1b  = (bf16_t*)w; w += (size_t)16384 * 1024 * 2;
  bf16_t* nx2  = (bf16_t*)w; w += (size_t)8192 * 768 * 2;
  bf16_t* WqT  = (bf16_t*)w; w += (size_t)1024 * 1024 * 2;
  bf16_t* WkT  = (bf16_t*)w; w += (size_t)1024 * 768 * 2;
  bf16_t* WvT  = (bf16_t*)w; w += (size_t)1024 * 768 * 2;
  bf16_t* WhT  = (bf16_t*)w; w += (size_t)1024 * 1024 * 2;
  bf16_t* qb   = (bf16_t*)w; w += (size_t)16384 * 1024 * 2;
  bf16_t* kbuf = (bf16_t*)w; w += (size_t)8192 * 1024 * 2;
  bf16_t* vbuf = (bf16_t*)w; w += (size_t)8192 * 1024 * 2;
  float*  part = (float*)w;  w += (size_t)64 * 8 * 64 * 64 * 4;
  bf16_t* attnT = (bf16_t*)w; w += (size_t)64 * 64 * 64 * 2;

  wprep_kernel<<<dim3(3584), dim3(256), 0, stream>>>(Wq, Wk, Wv, Wh, WqT, WkT, WvT, WhT);
  ln1_kernel<<<dim3(16384), dim3(256), 0, stream>>>(x1, g1, b1, nx1, x1b);
  ln2_kernel<<<dim3(8192), dim3(256), 0, stream>>>(x2, g2, b2, nx2);
  gemm_qkv_kernel<<<dim3(2048), dim3(256), 0, stream>>>(
      nx1, WqT, bq, qb, nx2, WkT, bk, kbuf, WvT, bv, vbuf);
  attn_partial_kernel<<<dim3(512), dim3(256), 0, stream>>>(kbuf, vbuf, part);
  attn_finalize_kernel<<<dim3(64), dim3(256), 0, stream>>>(part, attnT);
  gemm_final_kernel<<<dim3(128, 8), dim3(256), 0, stream>>>(x1b, WhT, bh, qb, attnT, out);
}